// Round 5
// baseline (385.260 us; speedup 1.0000x reference)
//
#include <hip/hip_runtime.h>

// TreeDecoderTeacherForced — R4: barrier-free conv loop. MFMA A-fragments are
// gathered per-lane directly from global (lane l = row l&15, 16B k-segment
// (l>>4)*16B), B-fragments read direct from pre-transposed Wt (L1-resident).
// No LDS/barriers in the K-loop; 1 barrier total (head transpose). Indices
// hoisted to registers up front; A prefetched one chunk ahead (full unroll).

using short8 = __attribute__((ext_vector_type(8))) short;
using f32x4  = __attribute__((ext_vector_type(4))) float;
typedef unsigned int u32;
typedef unsigned short u16;

constexpr int NPARENT = 200000;
constexpr int NCHILD  = 300000;

__device__ __forceinline__ u16 f2bf(float x) {        // fp32 -> bf16 RNE
    u32 u = __builtin_bit_cast(u32, x);
    u32 r = (u + 0x7fffu + ((u >> 16) & 1u)) >> 16;
    return (u16)r;
}
__device__ __forceinline__ float bf2f(u16 x) {
    u32 u = ((u32)x) << 16;
    return __builtin_bit_cast(float, u);
}
// swizzled byte offset in a [64 rows][64 bf16] tile (row stride 128 B).
__device__ __forceinline__ int swz(int row, int byteInRow) {
    return row * 128 + (byteInRow ^ ((row & 7) << 4));
}

// ---------------- fused prep: weights + feat->bf16 + child idx fusion ------
__global__ __launch_bounds__(256)
void prep_all(const float* __restrict__ W1, const float* __restrict__ W2,
              const float* __restrict__ Wv1, const float* __restrict__ Wv2,
              const float* __restrict__ feat,
              const int* __restrict__ neigh_d1, const int* __restrict__ parent_idx,
              const float* __restrict__ split_gt,
              u16* __restrict__ Wt1, u16* __restrict__ Wt2,
              u16* __restrict__ Wv1t, u16* __restrict__ Wv2t,
              u16* __restrict__ featb, int* __restrict__ fused,
              int bW, int bF, int doFeat, int doFuse)
{
    const int b = blockIdx.x;
    if (b < bW) {
        int t = b * 256 + threadIdx.x;
        if (t < 576 * 64) {
            int k = t >> 6, c = t & 63;
            Wt1[c * 576 + k] = f2bf(W1[t]);
            Wt2[c * 576 + k] = f2bf(W2[t]);
        }
        if (t < 64 * 64) {
            int k = t >> 6, c = t & 63;
            Wv1t[c * 64 + k] = f2bf(Wv1[t]);
            Wv2t[c * 64 + k] = f2bf(Wv2[t]);
        }
    } else if (b < bW + bF) {
        if (!doFeat) return;
        int t = (b - bW) * 256 + threadIdx.x;
        if (t < NPARENT * 64 / 8) {
            const float4 a = *reinterpret_cast<const float4*>(feat + (size_t)t * 8);
            const float4 c = *reinterpret_cast<const float4*>(feat + (size_t)t * 8 + 4);
            short8 o;
            o[0]=(short)f2bf(a.x); o[1]=(short)f2bf(a.y); o[2]=(short)f2bf(a.z); o[3]=(short)f2bf(a.w);
            o[4]=(short)f2bf(c.x); o[5]=(short)f2bf(c.y); o[6]=(short)f2bf(c.z); o[7]=(short)f2bf(c.w);
            *reinterpret_cast<short8*>(featb + (size_t)t * 8) = o;
        }
    } else {
        if (!doFuse) return;
        int t = (b - bW - bF) * 256 + threadIdx.x;
        if (t < NCHILD * 9) {
            int g = neigh_d1[t];
            int e = -1;
            if (g >= 0) {
                int p = parent_idx[g];
                if (split_gt[p] != 0.0f) e = p;
            }
            fused[t] = e;
        }
    }
}

// ---------------- main fused conv + heads kernel ----------------
// MODE: 0 = parent fp32 feat (fallback)  1 = parent bf16 feat
//       2 = child fused idx              3 = child unfused (fallback)
template<int MODE>
__global__ __launch_bounds__(256, 4)
void quad_direct(const float* __restrict__ src_f32,    // MODE 0
                 const u16*   __restrict__ src_b16,    // MODE 1: featb; 2/3: h
                 const int*   __restrict__ idx,        // 0/1/3: neigh; 2: fused
                 const int*   __restrict__ parent_idx, // MODE 3 only
                 const float* __restrict__ split_gt,   // MODE 3 only
                 const u16*   __restrict__ Wt,         // [64][576] bf16
                 const float* __restrict__ bvec,
                 const float* __restrict__ Ws,
                 const u16*   __restrict__ Wvt,        // [64][64] bf16
                 float* __restrict__ split_out,
                 float* __restrict__ value_out,
                 u16*   __restrict__ h_out,            // parent modes only
                 int N)
{
    __shared__ u16 hT[64 * 64];

    const int tid  = threadIdx.x;
    const int lane = tid & 63;
    const int w    = tid >> 6;
    const int cq   = lane & 15;
    const int kh   = lane >> 4;
    const int base = blockIdx.x * 64;
    const int arow = base + w * 16 + cq;     // this lane's gather row (node)

    // ---- hoist all 9 gather indices into registers (kills load chains) ----
    int gidx[9];
    #pragma unroll
    for (int j = 0; j < 9; ++j) gidx[j] = -1;
    if (arow < N) {
        #pragma unroll
        for (int j = 0; j < 9; ++j) gidx[j] = idx[(size_t)arow * 9 + j];
        if (MODE == 3) {
            #pragma unroll
            for (int j = 0; j < 9; ++j) {
                int g = gidx[j], e = -1;
                if (g >= 0) {
                    int p = parent_idx[g];
                    if (split_gt[p] != 0.0f) e = p;
                }
                gidx[j] = e;
            }
        }
    }

    // ---- accumulators: bias broadcast ----
    f32x4 acc[4];
    #pragma unroll
    for (int cf = 0; cf < 4; ++cf) {
        float b = bvec[cf * 16 + cq];
        acc[cf] = f32x4{b, b, b, b};
    }

    const short8 zero8 = short8{0,0,0,0,0,0,0,0};
    auto loadA = [&](int j, short8* d) {
        const int g = gidx[j];
        if (MODE == 0) {
            d[0] = zero8; d[1] = zero8;
            if (g >= 0) {
                const float* s = src_f32 + (size_t)g * 64 + kh * 8;
                #pragma unroll
                for (int ks = 0; ks < 2; ++ks) {
                    float4 x = *reinterpret_cast<const float4*>(s + ks * 32);
                    float4 y = *reinterpret_cast<const float4*>(s + ks * 32 + 4);
                    short8 o;
                    o[0]=(short)f2bf(x.x); o[1]=(short)f2bf(x.y); o[2]=(short)f2bf(x.z); o[3]=(short)f2bf(x.w);
                    o[4]=(short)f2bf(y.x); o[5]=(short)f2bf(y.y); o[6]=(short)f2bf(y.z); o[7]=(short)f2bf(y.w);
                    d[ks] = o;
                }
            }
        } else {
            if (g >= 0) {
                const u16* s = src_b16 + (size_t)g * 64 + kh * 8;
                d[0] = *reinterpret_cast<const short8*>(s);
                d[1] = *reinterpret_cast<const short8*>(s + 32);
            } else { d[0] = zero8; d[1] = zero8; }
        }
    };

    // ---- barrier-free conv loop, A prefetched one chunk ahead ----
    short8 aA[2], aB[2];
    loadA(0, aA);
    #pragma unroll
    for (int j = 0; j < 9; ++j) {
        short8* cur = (j & 1) ? aB : aA;
        short8* nxt = (j & 1) ? aA : aB;
        if (j < 8) loadA(j + 1, nxt);
        #pragma unroll
        for (int ks = 0; ks < 2; ++ks) {
            #pragma unroll
            for (int cf = 0; cf < 4; ++cf) {
                const u16* s = Wt + (size_t)(cf * 16 + cq) * 576 + j * 64 + ks * 32 + kh * 8;
                short8 bfrag = *reinterpret_cast<const short8*>(s);
                acc[cf] = __builtin_amdgcn_mfma_f32_16x16x32_bf16(cur[ks], bfrag, acc[cf], 0, 0, 0);
            }
        }
    }

    // ---- relu + stage hT (C-layout -> row-major bf16, swizzled) ----
    #pragma unroll
    for (int cf = 0; cf < 4; ++cf)
        #pragma unroll
        for (int r = 0; r < 4; ++r) {
            float hval = fmaxf(acc[cf][r], 0.f);
            int row = w * 16 + kh * 4 + r;          // C/D: row=(l>>4)*4+r
            int col = cf * 16 + cq;                  //      col=l&15 (+16*cf)
            *reinterpret_cast<u16*>((char*)hT + swz(row, col * 2)) = f2bf(hval);
        }

    // prefetch value-head B-fragments (independent of hT)
    short8 wvf[2][4];
    #pragma unroll
    for (int ks = 0; ks < 2; ++ks)
        #pragma unroll
        for (int cf = 0; cf < 4; ++cf)
            wvf[ks][cf] = *reinterpret_cast<const short8*>(
                Wvt + (size_t)(cf * 16 + cq) * 64 + ks * 32 + kh * 8);

    __syncthreads();

    // ---- value head: value = relu(h) @ Wv ----
    f32x4 vacc[4];
    #pragma unroll
    for (int cf = 0; cf < 4; ++cf) vacc[cf] = f32x4{0.f, 0.f, 0.f, 0.f};
    #pragma unroll
    for (int ks = 0; ks < 2; ++ks) {
        short8 af = *reinterpret_cast<const short8*>(
            (const char*)hT + swz(w * 16 + cq, ks * 64 + kh * 16));
        #pragma unroll
        for (int cf = 0; cf < 4; ++cf)
            vacc[cf] = __builtin_amdgcn_mfma_f32_16x16x32_bf16(af, wvf[ks][cf], vacc[cf], 0, 0, 0);
    }
    #pragma unroll
    for (int cf = 0; cf < 4; ++cf)
        #pragma unroll
        for (int r = 0; r < 4; ++r) {
            int node = base + w * 16 + kh * 4 + r;
            if (node < N)
                value_out[(size_t)node * 64 + cf * 16 + cq] = vacc[cf][r];
        }

    const int ln = tid >> 2;      // 0..63
    const int s  = tid & 3;       // 0..3

    // ---- parent: write bf16 h (ungated) to workspace, coalesced ----
    if (MODE == 0 || MODE == 1) {
        int node = base + ln;
        if (node < N) {
            short8 x0 = *reinterpret_cast<const short8*>((const char*)hT + swz(ln, s * 32));
            short8 x1 = *reinterpret_cast<const short8*>((const char*)hT + swz(ln, s * 32 + 16));
            u16* dst = h_out + (size_t)node * 64 + s * 16;
            *reinterpret_cast<short8*>(dst)     = x0;
            *reinterpret_cast<short8*>(dst + 8) = x1;
        }
    }

    // ---- split head: split[n] = dot(h[n], Ws) ----
    {
        float sp = 0.f;
        #pragma unroll
        for (int u2 = 0; u2 < 2; ++u2) {
            short8 hv = *reinterpret_cast<const short8*>((const char*)hT + swz(ln, s * 32 + u2 * 16));
            #pragma unroll
            for (int e = 0; e < 8; ++e)
                sp += bf2f((u16)hv[e]) * Ws[s * 16 + u2 * 8 + e];
        }
        sp += __shfl_xor(sp, 1);
        sp += __shfl_xor(sp, 2);
        if (s == 0) {
            int node = base + ln;
            if (node < N) split_out[node] = sp;
        }
    }
}

extern "C" void kernel_launch(void* const* d_in, const int* in_sizes, int n_in,
                              void* d_out, int out_size, void* d_ws, size_t ws_size,
                              hipStream_t stream) {
    const float* feat       = (const float*)d_in[0];
    const int*   neigh_d    = (const int*)d_in[1];
    const int*   neigh_d1   = (const int*)d_in[2];
    const int*   parent_idx = (const int*)d_in[3];
    const float* split_gt   = (const float*)d_in[4];
    const float* W1  = (const float*)d_in[5];
    const float* b1  = (const float*)d_in[6];
    const float* W2  = (const float*)d_in[7];
    const float* b2  = (const float*)d_in[8];
    const float* Ws1 = (const float*)d_in[9];
    const float* Wv1 = (const float*)d_in[10];
    const float* Ws2 = (const float*)d_in[11];
    const float* Wv2 = (const float*)d_in[12];

    float* out    = (float*)d_out;
    float* split1 = out;
    float* value1 = out + NPARENT;
    float* split2 = out + NPARENT + (size_t)NPARENT * 64;
    float* value2 = split2 + NCHILD;

    // ---- workspace layout ----
    u16* h_ws = (u16*)d_ws;                          // [200000][64] bf16, ungated
    u16* Wt1  = h_ws + (size_t)NPARENT * 64;
    u16* Wt2  = Wt1 + 576 * 64;
    u16* Wv1t = Wt2 + 576 * 64;
    u16* Wv2t = Wv1t + 64 * 64;
    u16* endW = Wv2t + 64 * 64;
    size_t offW_bytes = (size_t)(endW - (u16*)d_ws) * 2;

    int*  fused = (int*)((char*)d_ws + offW_bytes);  // [300000][9] int32
    size_t offF_bytes = offW_bytes + (size_t)NCHILD * 9 * 4;
    u16*  featb = (u16*)((char*)d_ws + offF_bytes);  // [200000][64] bf16
    size_t offB_bytes = offF_bytes + (size_t)NPARENT * 64 * 2;

    const bool useFused = ws_size >= offF_bytes;
    const bool useFeatb = ws_size >= offB_bytes;

    const int bW = 145;                              // 145*256 >= 576*64
    const int bF = (NPARENT * 64 / 8 + 255) / 256;   // feat bf16 conversion
    const int bI = (NCHILD * 9 + 255) / 256;         // idx fusion
    prep_all<<<bW + bF + bI, 256, 0, stream>>>(
        W1, W2, Wv1, Wv2, feat, neigh_d1, parent_idx, split_gt,
        Wt1, Wt2, Wv1t, Wv2t, featb, fused,
        bW, bF, useFeatb ? 1 : 0, useFused ? 1 : 0);

    if (useFeatb)
        quad_direct<1><<<NPARENT / 64, 256, 0, stream>>>(
            nullptr, featb, neigh_d, nullptr, nullptr,
            Wt1, b1, Ws1, Wv1t, split1, value1, h_ws, NPARENT);
    else
        quad_direct<0><<<NPARENT / 64, 256, 0, stream>>>(
            feat, nullptr, neigh_d, nullptr, nullptr,
            Wt1, b1, Ws1, Wv1t, split1, value1, h_ws, NPARENT);

    if (useFused)
        quad_direct<2><<<(NCHILD + 63) / 64, 256, 0, stream>>>(
            nullptr, h_ws, fused, nullptr, nullptr,
            Wt2, b2, Ws2, Wv2t, split2, value2, nullptr, NCHILD);
    else
        quad_direct<3><<<(NCHILD + 63) / 64, 256, 0, stream>>>(
            nullptr, h_ws, neigh_d1, parent_idx, split_gt,
            Wt2, b2, Ws2, Wv2t, split2, value2, nullptr, NCHILD);
}

// Round 6
// 355.061 us; speedup vs baseline: 1.0851x; 1.0851x over previous
//
#include <hip/hip_runtime.h>

// TreeDecoderTeacherForced — R5: R3's coalesced LDS staging for gathered A,
// restructured to ONE barrier per K-chunk (sync -> write buf(j+1) -> compute
// buf(j)), A-gather prefetched 2 chunks ahead in regs, W fragments direct
// global->reg (1 chunk ahead, no W LDS), indices hoisted to registers.
// LDS 24KB/block. prep: merged weights/feat/idx kernel (as R4).

using short8 = __attribute__((ext_vector_type(8))) short;
using us4    = __attribute__((ext_vector_type(4))) unsigned short;
using f32x4  = __attribute__((ext_vector_type(4))) float;
typedef unsigned int u32;
typedef unsigned short u16;

constexpr int NPARENT = 200000;
constexpr int NCHILD  = 300000;

__device__ __forceinline__ u16 f2bf(float x) {        // fp32 -> bf16 RNE
    u32 u = __builtin_bit_cast(u32, x);
    u32 r = (u + 0x7fffu + ((u >> 16) & 1u)) >> 16;
    return (u16)r;
}
__device__ __forceinline__ float bf2f(u16 x) {
    u32 u = ((u32)x) << 16;
    return __builtin_bit_cast(float, u);
}
// swizzled byte offset in a [64 rows][64 bf16] tile (row stride 128 B).
__device__ __forceinline__ int swz(int row, int byteInRow) {
    return row * 128 + (byteInRow ^ ((row & 7) << 4));
}

// ---------------- fused prep: weights + feat->bf16 + child idx fusion ------
__global__ __launch_bounds__(256)
void prep_all(const float* __restrict__ W1, const float* __restrict__ W2,
              const float* __restrict__ Wv1, const float* __restrict__ Wv2,
              const float* __restrict__ feat,
              const int* __restrict__ neigh_d1, const int* __restrict__ parent_idx,
              const float* __restrict__ split_gt,
              u16* __restrict__ Wt1, u16* __restrict__ Wt2,
              u16* __restrict__ Wv1t, u16* __restrict__ Wv2t,
              u16* __restrict__ featb, int* __restrict__ fused,
              int bW, int bF, int doFeat, int doFuse)
{
    const int b = blockIdx.x;
    if (b < bW) {
        int t = b * 256 + threadIdx.x;
        if (t < 576 * 64) {
            int k = t >> 6, c = t & 63;
            Wt1[c * 576 + k] = f2bf(W1[t]);
            Wt2[c * 576 + k] = f2bf(W2[t]);
        }
        if (t < 64 * 64) {
            int k = t >> 6, c = t & 63;
            Wv1t[c * 64 + k] = f2bf(Wv1[t]);
            Wv2t[c * 64 + k] = f2bf(Wv2[t]);
        }
    } else if (b < bW + bF) {
        if (!doFeat) return;
        int t = (b - bW) * 256 + threadIdx.x;
        if (t < NPARENT * 64 / 8) {
            const float4 a = *reinterpret_cast<const float4*>(feat + (size_t)t * 8);
            const float4 c = *reinterpret_cast<const float4*>(feat + (size_t)t * 8 + 4);
            short8 o;
            o[0]=(short)f2bf(a.x); o[1]=(short)f2bf(a.y); o[2]=(short)f2bf(a.z); o[3]=(short)f2bf(a.w);
            o[4]=(short)f2bf(c.x); o[5]=(short)f2bf(c.y); o[6]=(short)f2bf(c.z); o[7]=(short)f2bf(c.w);
            *reinterpret_cast<short8*>(featb + (size_t)t * 8) = o;
        }
    } else {
        if (!doFuse) return;
        int t = (b - bW - bF) * 256 + threadIdx.x;
        if (t < NCHILD * 9) {
            int g = neigh_d1[t];
            int e = -1;
            if (g >= 0) {
                int p = parent_idx[g];
                if (split_gt[p] != 0.0f) e = p;
            }
            fused[t] = e;
        }
    }
}

// ---------------- main fused conv + heads kernel ----------------
// MODE: 0 = parent fp32 feat (fallback)  1 = parent bf16 feat
//       2 = child fused idx              3 = child unfused (fallback)
template<int MODE>
__global__ __launch_bounds__(256)
void quad_hyb(const float* __restrict__ src_f32,    // MODE 0
              const u16*   __restrict__ src_b16,    // MODE 1: featb; 2/3: h
              const int*   __restrict__ idx,        // 0/1/3: neigh; 2: fused
              const int*   __restrict__ parent_idx, // MODE 3 only
              const float* __restrict__ split_gt,   // MODE 3 only
              const u16*   __restrict__ Wt,         // [64][576] bf16
              const float* __restrict__ bvec,
              const float* __restrict__ Ws,
              const u16*   __restrict__ Wvt,        // [64][64] bf16
              float* __restrict__ split_out,
              float* __restrict__ value_out,
              u16*   __restrict__ h_out,            // parent modes only
              int N)
{
    __shared__ u16 aL[2][64 * 64];   // gathered-A double buffer (swizzled)
    __shared__ u16 hT[64 * 64];      // relu'd hidden, row-major swizzled

    const int tid  = threadIdx.x;
    const int lane = tid & 63;
    const int w    = tid >> 6;
    const int cq   = lane & 15;
    const int kh   = lane >> 4;
    const int base = blockIdx.x * 64;
    const int ln   = tid >> 2;       // staging row 0..63
    const int s    = tid & 3;        // staging 16-col sub-slot

    // ---- hoist all 9 gather indices for this staging row ----
    int gidx[9];
    #pragma unroll
    for (int j = 0; j < 9; ++j) gidx[j] = -1;
    if (base + ln < N) {
        #pragma unroll
        for (int j = 0; j < 9; ++j) gidx[j] = idx[(size_t)(base + ln) * 9 + j];
        if (MODE == 3) {
            #pragma unroll
            for (int j = 0; j < 9; ++j) {
                int g = gidx[j], e = -1;
                if (g >= 0) {
                    int p = parent_idx[g];
                    if (split_gt[p] != 0.0f) e = p;
                }
                gidx[j] = e;
            }
        }
    }

    // ---- staging register sets ----
    const short8 zero8 = short8{0,0,0,0,0,0,0,0};
    short8 avS[2][2];                 // bf16 path: 2 sets x 32B
    float4 avP[2][4];                 // fp32 fallback path
    short8 bfS[2][4];                 // W fragments for current chunk (per-wave)

    auto issueA = [&](int j, int set) {
        const int g = gidx[j];
        if (MODE == 0) {
            #pragma unroll
            for (int u = 0; u < 4; ++u) avP[set][u] = make_float4(0.f,0.f,0.f,0.f);
            if (g >= 0) {
                const float* sp = src_f32 + (size_t)g * 64 + s * 16;
                #pragma unroll
                for (int u = 0; u < 4; ++u)
                    avP[set][u] = *reinterpret_cast<const float4*>(sp + u * 4);
            }
        } else {
            if (g >= 0) {
                const u16* sp = src_b16 + (size_t)g * 64 + s * 16;
                avS[set][0] = *reinterpret_cast<const short8*>(sp);
                avS[set][1] = *reinterpret_cast<const short8*>(sp + 8);
            } else { avS[set][0] = zero8; avS[set][1] = zero8; }
        }
    };
    auto writeA = [&](int set, int buf) {
        char* aB = (char*)aL[buf];
        if (MODE == 0) {
            #pragma unroll
            for (int u = 0; u < 4; ++u) {
                us4 t4 = { f2bf(avP[set][u].x), f2bf(avP[set][u].y),
                           f2bf(avP[set][u].z), f2bf(avP[set][u].w) };
                *reinterpret_cast<us4*>(aB + swz(ln, s * 32 + u * 8)) = t4;
            }
        } else {
            *reinterpret_cast<short8*>(aB + swz(ln, s * 32))      = avS[set][0];
            *reinterpret_cast<short8*>(aB + swz(ln, s * 32 + 16)) = avS[set][1];
        }
    };
    auto issueB = [&](int j) {
        #pragma unroll
        for (int ks = 0; ks < 2; ++ks)
            #pragma unroll
            for (int cf = 0; cf < 4; ++cf)
                bfS[ks][cf] = *reinterpret_cast<const short8*>(
                    Wt + (size_t)(cf * 16 + cq) * 576 + j * 64 + ks * 32 + kh * 8);
    };

    // ---- accumulators: bias broadcast ----
    f32x4 acc[4];
    #pragma unroll
    for (int cf = 0; cf < 4; ++cf) {
        float b = bvec[cf * 16 + cq];
        acc[cf] = f32x4{b, b, b, b};
    }

    auto computeChunk = [&](int buf, f32x4* ac) {
        const char* aB = (const char*)aL[buf];
        #pragma unroll
        for (int ks = 0; ks < 2; ++ks) {
            short8 afrag = *reinterpret_cast<const short8*>(
                aB + swz(w * 16 + cq, ks * 64 + kh * 16));
            #pragma unroll
            for (int cf = 0; cf < 4; ++cf)
                ac[cf] = __builtin_amdgcn_mfma_f32_16x16x32_bf16(afrag, bfS[ks][cf], ac[cf], 0, 0, 0);
        }
    };

    // ---- prologue: A(0),A(1),B(0) in flight; A(0) -> LDS ----
    issueA(0, 0); issueA(1, 1); issueB(0);
    writeA(0, 0);

    // ---- conv loop: ONE barrier per chunk ----
    // iter j: issue A(j+2) | sync | write A(j+1)->aL[(j+1)&1] | compute(aL[j&1]) | issue B(j+1)
    #pragma unroll
    for (int j = 0; j < 9; ++j) {
        if (j <= 6) issueA(j + 2, j & 1);
        __syncthreads();
        if (j < 8) writeA((j + 1) & 1, (j + 1) & 1);
        computeChunk(j & 1, acc);
        if (j < 8) issueB(j + 1);
    }

    // ---- relu + stage hT (C-layout -> row-major bf16, swizzled) ----
    short8 wvf[2][4];
    #pragma unroll
    for (int ks = 0; ks < 2; ++ks)          // value-head B frags fly during VALU work
        #pragma unroll
        for (int cf = 0; cf < 4; ++cf)
            wvf[ks][cf] = *reinterpret_cast<const short8*>(
                Wvt + (size_t)(cf * 16 + cq) * 64 + ks * 32 + kh * 8);
    #pragma unroll
    for (int cf = 0; cf < 4; ++cf)
        #pragma unroll
        for (int r = 0; r < 4; ++r) {
            float hval = fmaxf(acc[cf][r], 0.f);
            int row = w * 16 + kh * 4 + r;          // C/D: row=(l>>4)*4+r
            int col = cf * 16 + cq;                  //      col=l&15 (+16*cf)
            *reinterpret_cast<u16*>((char*)hT + swz(row, col * 2)) = f2bf(hval);
        }
    __syncthreads();

    // ---- value head: value = relu(h) @ Wv ----
    f32x4 vacc[4];
    #pragma unroll
    for (int cf = 0; cf < 4; ++cf) vacc[cf] = f32x4{0.f, 0.f, 0.f, 0.f};
    #pragma unroll
    for (int ks = 0; ks < 2; ++ks) {
        short8 af = *reinterpret_cast<const short8*>(
            (const char*)hT + swz(w * 16 + cq, ks * 64 + kh * 16));
        #pragma unroll
        for (int cf = 0; cf < 4; ++cf)
            vacc[cf] = __builtin_amdgcn_mfma_f32_16x16x32_bf16(af, wvf[ks][cf], vacc[cf], 0, 0, 0);
    }
    #pragma unroll
    for (int cf = 0; cf < 4; ++cf)
        #pragma unroll
        for (int r = 0; r < 4; ++r) {
            int node = base + w * 16 + kh * 4 + r;
            if (node < N)
                value_out[(size_t)node * 64 + cf * 16 + cq] = vacc[cf][r];
        }

    // ---- parent: write bf16 h (ungated) to workspace, coalesced ----
    if (MODE == 0 || MODE == 1) {
        int node = base + ln;
        if (node < N) {
            short8 x0 = *reinterpret_cast<const short8*>((const char*)hT + swz(ln, s * 32));
            short8 x1 = *reinterpret_cast<const short8*>((const char*)hT + swz(ln, s * 32 + 16));
            u16* dst = h_out + (size_t)node * 64 + s * 16;
            *reinterpret_cast<short8*>(dst)     = x0;
            *reinterpret_cast<short8*>(dst + 8) = x1;
        }
    }

    // ---- split head: split[n] = dot(h[n], Ws) ----
    {
        float sp = 0.f;
        #pragma unroll
        for (int u2 = 0; u2 < 2; ++u2) {
            short8 hv = *reinterpret_cast<const short8*>(
                (const char*)hT + swz(ln, s * 32 + u2 * 16));
            #pragma unroll
            for (int e = 0; e < 8; ++e)
                sp += bf2f((u16)hv[e]) * Ws[s * 16 + u2 * 8 + e];
        }
        sp += __shfl_xor(sp, 1);
        sp += __shfl_xor(sp, 2);
        if (s == 0) {
            int node = base + ln;
            if (node < N) split_out[node] = sp;
        }
    }
}

extern "C" void kernel_launch(void* const* d_in, const int* in_sizes, int n_in,
                              void* d_out, int out_size, void* d_ws, size_t ws_size,
                              hipStream_t stream) {
    const float* feat       = (const float*)d_in[0];
    const int*   neigh_d    = (const int*)d_in[1];
    const int*   neigh_d1   = (const int*)d_in[2];
    const int*   parent_idx = (const int*)d_in[3];
    const float* split_gt   = (const float*)d_in[4];
    const float* W1  = (const float*)d_in[5];
    const float* b1  = (const float*)d_in[6];
    const float* W2  = (const float*)d_in[7];
    const float* b2  = (const float*)d_in[8];
    const float* Ws1 = (const float*)d_in[9];
    const float* Wv1 = (const float*)d_in[10];
    const float* Ws2 = (const float*)d_in[11];
    const float* Wv2 = (const float*)d_in[12];

    float* out    = (float*)d_out;
    float* split1 = out;
    float* value1 = out + NPARENT;
    float* split2 = out + NPARENT + (size_t)NPARENT * 64;
    float* value2 = split2 + NCHILD;

    // ---- workspace layout ----
    u16* h_ws = (u16*)d_ws;                          // [200000][64] bf16, ungated
    u16* Wt1  = h_ws + (size_t)NPARENT * 64;
    u16* Wt2  = Wt1 + 576 * 64;
    u16* Wv1t = Wt2 + 576 * 64;
    u16* Wv2t = Wv1t + 64 * 64;
    u16* endW = Wv2t + 64 * 64;
    size_t offW_bytes = (size_t)(endW - (u16*)d_ws) * 2;

    int*  fused = (int*)((char*)d_ws + offW_bytes);  // [300000][9] int32
    size_t offF_bytes = offW_bytes + (size_t)NCHILD * 9 * 4;
    u16*  featb = (u16*)((char*)d_ws + offF_bytes);  // [200000][64] bf16
    size_t offB_bytes = offF_bytes + (size_t)NPARENT * 64 * 2;

    const bool useFused = ws_size >= offF_bytes;
    const bool useFeatb = ws_size >= offB_bytes;

    const int bW = 145;                              // 145*256 >= 576*64
    const int bF = (NPARENT * 64 / 8 + 255) / 256;   // feat bf16 conversion
    const int bI = (NCHILD * 9 + 255) / 256;         // idx fusion
    prep_all<<<bW + bF + bI, 256, 0, stream>>>(
        W1, W2, Wv1, Wv2, feat, neigh_d1, parent_idx, split_gt,
        Wt1, Wt2, Wv1t, Wv2t, featb, fused,
        bW, bF, useFeatb ? 1 : 0, useFused ? 1 : 0);

    if (useFeatb)
        quad_hyb<1><<<NPARENT / 64, 256, 0, stream>>>(
            nullptr, featb, neigh_d, nullptr, nullptr,
            Wt1, b1, Ws1, Wv1t, split1, value1, h_ws, NPARENT);
    else
        quad_hyb<0><<<NPARENT / 64, 256, 0, stream>>>(
            feat, nullptr, neigh_d, nullptr, nullptr,
            Wt1, b1, Ws1, Wv1t, split1, value1, h_ws, NPARENT);

    if (useFused)
        quad_hyb<2><<<(NCHILD + 63) / 64, 256, 0, stream>>>(
            nullptr, h_ws, fused, nullptr, nullptr,
            Wt2, b2, Ws2, Wv2t, split2, value2, nullptr, NCHILD);
    else
        quad_hyb<3><<<(NCHILD + 63) / 64, 256, 0, stream>>>(
            nullptr, h_ws, neigh_d1, parent_idx, split_gt,
            Wt2, b2, Ws2, Wv2t, split2, value2, nullptr, NCHILD);
}

// Round 7
// 151.288 us; speedup vs baseline: 2.5465x; 2.3469x over previous
//
#include <hip/hip_runtime.h>

// TreeDecoderTeacherForced — R6: R3's proven structure (coalesced LDS staging
// for A and W, XOR swizzle, 2 barriers/chunk, fused child idx, bf16 feat)
// + depth-2 A-gather prefetch (misses stay in flight across the vmcnt stall)
// + __launch_bounds__(256,5) for 5-block/CU capacity.
// Lesson from R4/R5: W must be LDS-staged; per-wave divergent global W reads
// on the MFMA feed path cost ~2x.

using short8 = __attribute__((ext_vector_type(8))) short;
using us4    = __attribute__((ext_vector_type(4))) unsigned short;
using f32x4  = __attribute__((ext_vector_type(4))) float;
typedef unsigned int u32;
typedef unsigned short u16;

constexpr int NPARENT = 200000;
constexpr int NCHILD  = 300000;

__device__ __forceinline__ u16 f2bf(float x) {        // fp32 -> bf16 RNE
    u32 u = __builtin_bit_cast(u32, x);
    u32 r = (u + 0x7fffu + ((u >> 16) & 1u)) >> 16;
    return (u16)r;
}
__device__ __forceinline__ float bf2f(u16 x) {
    u32 u = ((u32)x) << 16;
    return __builtin_bit_cast(float, u);
}
// swizzled byte offset in a [64 rows][64 bf16] tile (row stride 128 B).
__device__ __forceinline__ int swz(int row, int byteInRow) {
    return row * 128 + (byteInRow ^ ((row & 7) << 4));
}

// ---------------- fused prep: weights + feat->bf16 + child idx fusion ------
__global__ __launch_bounds__(256)
void prep_all(const float* __restrict__ W1, const float* __restrict__ W2,
              const float* __restrict__ Wv1, const float* __restrict__ Wv2,
              const float* __restrict__ feat,
              const int* __restrict__ neigh_d1, const int* __restrict__ parent_idx,
              const float* __restrict__ split_gt,
              u16* __restrict__ Wt1, u16* __restrict__ Wt2,
              u16* __restrict__ Wv1t, u16* __restrict__ Wv2t,
              u16* __restrict__ featb, int* __restrict__ fused,
              int bW, int bF, int doFeat, int doFuse)
{
    const int b = blockIdx.x;
    if (b < bW) {
        int t = b * 256 + threadIdx.x;
        if (t < 576 * 64) {
            int k = t >> 6, c = t & 63;
            Wt1[c * 576 + k] = f2bf(W1[t]);
            Wt2[c * 576 + k] = f2bf(W2[t]);
        }
        if (t < 64 * 64) {
            int k = t >> 6, c = t & 63;
            Wv1t[c * 64 + k] = f2bf(Wv1[t]);
            Wv2t[c * 64 + k] = f2bf(Wv2[t]);
        }
    } else if (b < bW + bF) {
        if (!doFeat) return;
        int t = (b - bW) * 256 + threadIdx.x;
        if (t < NPARENT * 64 / 8) {
            const float4 a = *reinterpret_cast<const float4*>(feat + (size_t)t * 8);
            const float4 c = *reinterpret_cast<const float4*>(feat + (size_t)t * 8 + 4);
            short8 o;
            o[0]=(short)f2bf(a.x); o[1]=(short)f2bf(a.y); o[2]=(short)f2bf(a.z); o[3]=(short)f2bf(a.w);
            o[4]=(short)f2bf(c.x); o[5]=(short)f2bf(c.y); o[6]=(short)f2bf(c.z); o[7]=(short)f2bf(c.w);
            *reinterpret_cast<short8*>(featb + (size_t)t * 8) = o;
        }
    } else {
        if (!doFuse) return;
        int t = (b - bW - bF) * 256 + threadIdx.x;
        if (t < NCHILD * 9) {
            int g = neigh_d1[t];
            int e = -1;
            if (g >= 0) {
                int p = parent_idx[g];
                if (split_gt[p] != 0.0f) e = p;
            }
            fused[t] = e;
        }
    }
}

// ---------------- main fused conv + heads kernel ----------------
// MODE: 0 = parent fp32 feat (fallback)  1 = parent bf16 feat
//       2 = child fused idx              3 = child unfused (fallback)
template<int MODE>
__global__ __launch_bounds__(256, 5)
void quad_mfma(const float*  __restrict__ src_f32,    // MODE 0
               const u16*    __restrict__ src_b16,    // MODE 1: featb; 2/3: h
               const int*    __restrict__ idx,        // 0/1/3: neigh; 2: fused
               const int*    __restrict__ parent_idx, // MODE 3 only
               const float*  __restrict__ split_gt,   // MODE 3 only
               const u16*    __restrict__ Wt,         // [64][576] bf16
               const float*  __restrict__ bvec,
               const float*  __restrict__ Ws,
               const u16*    __restrict__ Wvt,        // [64][64] bf16
               float* __restrict__ split_out,
               float* __restrict__ value_out,
               u16*   __restrict__ h_out,             // parent modes only
               int N)
{
    __shared__ u16 aL[2][64 * 64];
    __shared__ u16 wL[2][64 * 64];

    const int tid  = threadIdx.x;
    const int lane = tid & 63;
    const int w    = tid >> 6;
    const int cq   = lane & 15;
    const int kh   = lane >> 4;
    const int base = blockIdx.x * 64;
    const int ln   = tid >> 2;        // staging row 0..63
    const int s    = tid & 3;         // staging 16-col sub-slot

    // ---- hoist all 9 gather indices for this staging row ----
    int gidx[9];
    #pragma unroll
    for (int j = 0; j < 9; ++j) gidx[j] = -1;
    if (base + ln < N) {
        #pragma unroll
        for (int j = 0; j < 9; ++j) gidx[j] = idx[(size_t)(base + ln) * 9 + j];
        if (MODE == 3) {
            #pragma unroll
            for (int j = 0; j < 9; ++j) {
                int g = gidx[j], e = -1;
                if (g >= 0) {
                    int p = parent_idx[g];
                    if (split_gt[p] != 0.0f) e = p;
                }
                gidx[j] = e;
            }
        }
    }

    // ---- staging registers: TWO A-sets (depth-2 prefetch), one W set ----
    const short8 zero8 = short8{0,0,0,0,0,0,0,0};
    short8 avS[2][2];                 // bf16 A path
    float4 avP[2][4];                 // fp32 A fallback
    short8 wv2[2];                    // W staging regs

    auto issueA = [&](int j, int set) {
        const int g = gidx[j];
        if (MODE == 0) {
            #pragma unroll
            for (int u = 0; u < 4; ++u) avP[set][u] = make_float4(0.f,0.f,0.f,0.f);
            if (g >= 0) {
                const float* sp = src_f32 + (size_t)g * 64 + s * 16;
                #pragma unroll
                for (int u = 0; u < 4; ++u)
                    avP[set][u] = *reinterpret_cast<const float4*>(sp + u * 4);
            }
        } else {
            if (g >= 0) {
                const u16* sp = src_b16 + (size_t)g * 64 + s * 16;
                avS[set][0] = *reinterpret_cast<const short8*>(sp);
                avS[set][1] = *reinterpret_cast<const short8*>(sp + 8);
            } else { avS[set][0] = zero8; avS[set][1] = zero8; }
        }
    };
    auto writeA = [&](int set, int buf) {
        char* aB = (char*)aL[buf];
        if (MODE == 0) {
            #pragma unroll
            for (int u = 0; u < 4; ++u) {
                us4 t4 = { f2bf(avP[set][u].x), f2bf(avP[set][u].y),
                           f2bf(avP[set][u].z), f2bf(avP[set][u].w) };
                *reinterpret_cast<us4*>(aB + swz(ln, s * 32 + u * 8)) = t4;
            }
        } else {
            *reinterpret_cast<short8*>(aB + swz(ln, s * 32))      = avS[set][0];
            *reinterpret_cast<short8*>(aB + swz(ln, s * 32 + 16)) = avS[set][1];
        }
    };
    auto issueW = [&](int j) {
        const u16* src = Wt + (size_t)ln * 576 + j * 64 + s * 16;
        wv2[0] = *reinterpret_cast<const short8*>(src);
        wv2[1] = *reinterpret_cast<const short8*>(src + 8);
    };
    auto writeW = [&](int buf) {
        char* wB = (char*)wL[buf];
        *reinterpret_cast<short8*>(wB + swz(ln, s * 32))      = wv2[0];
        *reinterpret_cast<short8*>(wB + swz(ln, s * 32 + 16)) = wv2[1];
    };
    auto stageWv = [&]() {
        const u16* src = Wvt + (size_t)ln * 64 + s * 16;
        short8 a = *reinterpret_cast<const short8*>(src);
        short8 b = *reinterpret_cast<const short8*>(src + 8);
        char* wB = (char*)wL[1];
        *reinterpret_cast<short8*>(wB + swz(ln, s * 32))      = a;
        *reinterpret_cast<short8*>(wB + swz(ln, s * 32 + 16)) = b;
    };

    // ---- accumulators: bias broadcast ----
    f32x4 acc[4];
    #pragma unroll
    for (int cf = 0; cf < 4; ++cf) {
        float b = bvec[cf * 16 + cq];
        acc[cf] = f32x4{b, b, b, b};
    }

    auto computeChunk = [&](int buf, f32x4* ac) {
        const char* aB = (const char*)aL[buf];
        const char* wB = (const char*)wL[buf];
        #pragma unroll
        for (int ks = 0; ks < 2; ++ks) {
            short8 afrag = *reinterpret_cast<const short8*>(
                aB + swz(w * 16 + cq, ks * 64 + kh * 16));
            #pragma unroll
            for (int cf = 0; cf < 4; ++cf) {
                short8 bfrag = *reinterpret_cast<const short8*>(
                    wB + swz(cf * 16 + cq, ks * 64 + kh * 16));
                ac[cf] = __builtin_amdgcn_mfma_f32_16x16x32_bf16(afrag, bfrag, ac[cf], 0, 0, 0);
            }
        }
    };

    // ---- prologue: A(0)->set0, A(1)->set1 in flight; A(0),W(0) -> LDS ----
    issueA(0, 0); issueA(1, 1); issueW(0);
    writeA(0, 0); writeW(0);
    __syncthreads();

    // ---- conv loop: 2 barriers/chunk, A prefetched 2 ahead ----
    // iter j: issue A(j+2)->set(j&1) | issue W(j+1) | compute buf(j&1) | sync
    //         | write A(j+1) (set (j+1)&1) + W(j+1) -> buf((j+1)&1) | sync
    for (int j = 0; j < 9; ++j) {
        if (j <= 6) issueA(j + 2, j & 1);
        if (j < 8) issueW(j + 1);
        computeChunk(j & 1, acc);
        __syncthreads();
        if (j < 8) {
            writeA((j + 1) & 1, (j + 1) & 1);
            writeW((j + 1) & 1);
        } else {
            // final chunk: stage head weights + relu'd hT into free buffers
            stageWv();
            char* hB = (char*)aL[1];
            #pragma unroll
            for (int cf = 0; cf < 4; ++cf)
                #pragma unroll
                for (int r = 0; r < 4; ++r) {
                    float hval = fmaxf(acc[cf][r], 0.f);
                    int row = w * 16 + kh * 4 + r;       // C/D: row=(l>>4)*4+r
                    int col = cf * 16 + cq;              //      col=l&15 (+16*cf)
                    *reinterpret_cast<u16*>(hB + swz(row, col * 2)) = f2bf(hval);
                }
        }
        __syncthreads();
    }

    // ---- value head: value = relu(h) @ Wv  (aL[1]=hT, wL[1]=Wv) ----
    f32x4 vacc[4];
    #pragma unroll
    for (int cf = 0; cf < 4; ++cf) vacc[cf] = f32x4{0.f, 0.f, 0.f, 0.f};
    computeChunk(1, vacc);

    #pragma unroll
    for (int cf = 0; cf < 4; ++cf)
        #pragma unroll
        for (int r = 0; r < 4; ++r) {
            int node = base + w * 16 + kh * 4 + r;
            if (node < N)
                value_out[(size_t)node * 64 + cf * 16 + cq] = vacc[cf][r];
        }

    // ---- parent: write bf16 h (ungated) to workspace, coalesced ----
    if (MODE == 0 || MODE == 1) {
        int node = base + ln;
        if (node < N) {
            const char* hB = (const char*)aL[1];
            short8 x0 = *reinterpret_cast<const short8*>(hB + swz(ln, s * 32));
            short8 x1 = *reinterpret_cast<const short8*>(hB + swz(ln, s * 32 + 16));
            u16* dst = h_out + (size_t)node * 64 + s * 16;
            *reinterpret_cast<short8*>(dst)     = x0;
            *reinterpret_cast<short8*>(dst + 8) = x1;
        }
    }

    // ---- split head: split[n] = dot(h[n], Ws) ----
    {
        const char* hB = (const char*)aL[1];
        float sp = 0.f;
        #pragma unroll
        for (int u2 = 0; u2 < 2; ++u2) {
            short8 hv = *reinterpret_cast<const short8*>(hB + swz(ln, s * 32 + u2 * 16));
            #pragma unroll
            for (int e = 0; e < 8; ++e)
                sp += bf2f((u16)hv[e]) * Ws[s * 16 + u2 * 8 + e];
        }
        sp += __shfl_xor(sp, 1);
        sp += __shfl_xor(sp, 2);
        if (s == 0) {
            int node = base + ln;
            if (node < N) split_out[node] = sp;
        }
    }
}

extern "C" void kernel_launch(void* const* d_in, const int* in_sizes, int n_in,
                              void* d_out, int out_size, void* d_ws, size_t ws_size,
                              hipStream_t stream) {
    const float* feat       = (const float*)d_in[0];
    const int*   neigh_d    = (const int*)d_in[1];
    const int*   neigh_d1   = (const int*)d_in[2];
    const int*   parent_idx = (const int*)d_in[3];
    const float* split_gt   = (const float*)d_in[4];
    const float* W1  = (const float*)d_in[5];
    const float* b1  = (const float*)d_in[6];
    const float* W2  = (const float*)d_in[7];
    const float* b2  = (const float*)d_in[8];
    const float* Ws1 = (const float*)d_in[9];
    const float* Wv1 = (const float*)d_in[10];
    const float* Ws2 = (const float*)d_in[11];
    const float* Wv2 = (const float*)d_in[12];

    float* out    = (float*)d_out;
    float* split1 = out;
    float* value1 = out + NPARENT;
    float* split2 = out + NPARENT + (size_t)NPARENT * 64;
    float* value2 = split2 + NCHILD;

    // ---- workspace layout ----
    u16* h_ws = (u16*)d_ws;                          // [200000][64] bf16, ungated
    u16* Wt1  = h_ws + (size_t)NPARENT * 64;
    u16* Wt2  = Wt1 + 576 * 64;
    u16* Wv1t = Wt2 + 576 * 64;
    u16* Wv2t = Wv1t + 64 * 64;
    u16* endW = Wv2t + 64 * 64;
    size_t offW_bytes = (size_t)(endW - (u16*)d_ws) * 2;

    int*  fused = (int*)((char*)d_ws + offW_bytes);  // [300000][9] int32
    size_t offF_bytes = offW_bytes + (size_t)NCHILD * 9 * 4;
    u16*  featb = (u16*)((char*)d_ws + offF_bytes);  // [200000][64] bf16
    size_t offB_bytes = offF_bytes + (size_t)NPARENT * 64 * 2;

    const bool useFused = ws_size >= offF_bytes;
    const bool useFeatb = ws_size >= offB_bytes;

    const int bW = 145;                              // 145*256 >= 576*64
    const int bF = (NPARENT * 64 / 8 + 255) / 256;   // feat bf16 conversion
    const int bI = (NCHILD * 9 + 255) / 256;         // idx fusion
    prep_all<<<bW + bF + bI, 256, 0, stream>>>(
        W1, W2, Wv1, Wv2, feat, neigh_d1, parent_idx, split_gt,
        Wt1, Wt2, Wv1t, Wv2t, featb, fused,
        bW, bF, useFeatb ? 1 : 0, useFused ? 1 : 0);

    if (useFeatb)
        quad_mfma<1><<<NPARENT / 64, 256, 0, stream>>>(
            nullptr, featb, neigh_d, nullptr, nullptr,
            Wt1, b1, Ws1, Wv1t, split1, value1, h_ws, NPARENT);
    else
        quad_mfma<0><<<NPARENT / 64, 256, 0, stream>>>(
            feat, nullptr, neigh_d, nullptr, nullptr,
            Wt1, b1, Ws1, Wv1t, split1, value1, h_ws, NPARENT);

    if (useFused)
        quad_mfma<2><<<(NCHILD + 63) / 64, 256, 0, stream>>>(
            nullptr, h_ws, fused, nullptr, nullptr,
            Wt2, b2, Ws2, Wv2t, split2, value2, nullptr, NCHILD);
    else
        quad_mfma<3><<<(NCHILD + 63) / 64, 256, 0, stream>>>(
            nullptr, h_ws, neigh_d1, parent_idx, split_gt,
            Wt2, b2, Ws2, Wv2t, split2, value2, nullptr, NCHILD);
}

// Round 8
// 149.944 us; speedup vs baseline: 2.5694x; 1.0090x over previous
//
#include <hip/hip_runtime.h>

// TreeDecoderTeacherForced — R7: R6 + non-temporal stores for all streaming
// outputs (value1/value2/split1/split2 = 128 MB/iter). Theory: these writes
// thrash the memory-side L3 and evict the gathered h/featb working set
// (child FETCH 86 MB vs 36 MB compulsory). NT stores keep h/featb L3-resident
// -> gather latency ~halves -> latency-bound gather throughput ~doubles.
// h_out stays cached (read by child). Everything else identical to R6.

using short8 = __attribute__((ext_vector_type(8))) short;
using us4    = __attribute__((ext_vector_type(4))) unsigned short;
using f32x4  = __attribute__((ext_vector_type(4))) float;
typedef unsigned int u32;
typedef unsigned short u16;

constexpr int NPARENT = 200000;
constexpr int NCHILD  = 300000;

__device__ __forceinline__ u16 f2bf(float x) {        // fp32 -> bf16 RNE
    u32 u = __builtin_bit_cast(u32, x);
    u32 r = (u + 0x7fffu + ((u >> 16) & 1u)) >> 16;
    return (u16)r;
}
__device__ __forceinline__ float bf2f(u16 x) {
    u32 u = ((u32)x) << 16;
    return __builtin_bit_cast(float, u);
}
// swizzled byte offset in a [64 rows][64 bf16] tile (row stride 128 B).
__device__ __forceinline__ int swz(int row, int byteInRow) {
    return row * 128 + (byteInRow ^ ((row & 7) << 4));
}

// ---------------- fused prep: weights + feat->bf16 + child idx fusion ------
__global__ __launch_bounds__(256)
void prep_all(const float* __restrict__ W1, const float* __restrict__ W2,
              const float* __restrict__ Wv1, const float* __restrict__ Wv2,
              const float* __restrict__ feat,
              const int* __restrict__ neigh_d1, const int* __restrict__ parent_idx,
              const float* __restrict__ split_gt,
              u16* __restrict__ Wt1, u16* __restrict__ Wt2,
              u16* __restrict__ Wv1t, u16* __restrict__ Wv2t,
              u16* __restrict__ featb, int* __restrict__ fused,
              int bW, int bF, int doFeat, int doFuse)
{
    const int b = blockIdx.x;
    if (b < bW) {
        int t = b * 256 + threadIdx.x;
        if (t < 576 * 64) {
            int k = t >> 6, c = t & 63;
            Wt1[c * 576 + k] = f2bf(W1[t]);
            Wt2[c * 576 + k] = f2bf(W2[t]);
        }
        if (t < 64 * 64) {
            int k = t >> 6, c = t & 63;
            Wv1t[c * 64 + k] = f2bf(Wv1[t]);
            Wv2t[c * 64 + k] = f2bf(Wv2[t]);
        }
    } else if (b < bW + bF) {
        if (!doFeat) return;
        int t = (b - bW) * 256 + threadIdx.x;
        if (t < NPARENT * 64 / 8) {
            // NT loads: feat is read exactly once — don't pollute L3 with it.
            const f32x4 a = __builtin_nontemporal_load(
                reinterpret_cast<const f32x4*>(feat + (size_t)t * 8));
            const f32x4 c = __builtin_nontemporal_load(
                reinterpret_cast<const f32x4*>(feat + (size_t)t * 8 + 4));
            short8 o;
            o[0]=(short)f2bf(a[0]); o[1]=(short)f2bf(a[1]); o[2]=(short)f2bf(a[2]); o[3]=(short)f2bf(a[3]);
            o[4]=(short)f2bf(c[0]); o[5]=(short)f2bf(c[1]); o[6]=(short)f2bf(c[2]); o[7]=(short)f2bf(c[3]);
            *reinterpret_cast<short8*>(featb + (size_t)t * 8) = o;
        }
    } else {
        if (!doFuse) return;
        int t = (b - bW - bF) * 256 + threadIdx.x;
        if (t < NCHILD * 9) {
            int g = neigh_d1[t];
            int e = -1;
            if (g >= 0) {
                int p = parent_idx[g];
                if (split_gt[p] != 0.0f) e = p;
            }
            fused[t] = e;
        }
    }
}

// ---------------- main fused conv + heads kernel ----------------
// MODE: 0 = parent fp32 feat (fallback)  1 = parent bf16 feat
//       2 = child fused idx              3 = child unfused (fallback)
template<int MODE>
__global__ __launch_bounds__(256, 5)
void quad_mfma(const float*  __restrict__ src_f32,    // MODE 0
               const u16*    __restrict__ src_b16,    // MODE 1: featb; 2/3: h
               const int*    __restrict__ idx,        // 0/1/3: neigh; 2: fused
               const int*    __restrict__ parent_idx, // MODE 3 only
               const float*  __restrict__ split_gt,   // MODE 3 only
               const u16*    __restrict__ Wt,         // [64][576] bf16
               const float*  __restrict__ bvec,
               const float*  __restrict__ Ws,
               const u16*    __restrict__ Wvt,        // [64][64] bf16
               float* __restrict__ split_out,
               float* __restrict__ value_out,
               u16*   __restrict__ h_out,             // parent modes only
               int N)
{
    __shared__ u16 aL[2][64 * 64];
    __shared__ u16 wL[2][64 * 64];

    const int tid  = threadIdx.x;
    const int lane = tid & 63;
    const int w    = tid >> 6;
    const int cq   = lane & 15;
    const int kh   = lane >> 4;
    const int base = blockIdx.x * 64;
    const int ln   = tid >> 2;        // staging row 0..63
    const int s    = tid & 3;         // staging 16-col sub-slot

    // ---- hoist all 9 gather indices for this staging row ----
    int gidx[9];
    #pragma unroll
    for (int j = 0; j < 9; ++j) gidx[j] = -1;
    if (base + ln < N) {
        #pragma unroll
        for (int j = 0; j < 9; ++j) gidx[j] = idx[(size_t)(base + ln) * 9 + j];
        if (MODE == 3) {
            #pragma unroll
            for (int j = 0; j < 9; ++j) {
                int g = gidx[j], e = -1;
                if (g >= 0) {
                    int p = parent_idx[g];
                    if (split_gt[p] != 0.0f) e = p;
                }
                gidx[j] = e;
            }
        }
    }

    // ---- staging registers: TWO A-sets (depth-2 prefetch), one W set ----
    const short8 zero8 = short8{0,0,0,0,0,0,0,0};
    short8 avS[2][2];                 // bf16 A path
    float4 avP[2][4];                 // fp32 A fallback
    short8 wv2[2];                    // W staging regs

    auto issueA = [&](int j, int set) {
        const int g = gidx[j];
        if (MODE == 0) {
            #pragma unroll
            for (int u = 0; u < 4; ++u) avP[set][u] = make_float4(0.f,0.f,0.f,0.f);
            if (g >= 0) {
                const float* sp = src_f32 + (size_t)g * 64 + s * 16;
                #pragma unroll
                for (int u = 0; u < 4; ++u)
                    avP[set][u] = *reinterpret_cast<const float4*>(sp + u * 4);
            }
        } else {
            if (g >= 0) {
                const u16* sp = src_b16 + (size_t)g * 64 + s * 16;
                avS[set][0] = *reinterpret_cast<const short8*>(sp);
                avS[set][1] = *reinterpret_cast<const short8*>(sp + 8);
            } else { avS[set][0] = zero8; avS[set][1] = zero8; }
        }
    };
    auto writeA = [&](int set, int buf) {
        char* aB = (char*)aL[buf];
        if (MODE == 0) {
            #pragma unroll
            for (int u = 0; u < 4; ++u) {
                us4 t4 = { f2bf(avP[set][u].x), f2bf(avP[set][u].y),
                           f2bf(avP[set][u].z), f2bf(avP[set][u].w) };
                *reinterpret_cast<us4*>(aB + swz(ln, s * 32 + u * 8)) = t4;
            }
        } else {
            *reinterpret_cast<short8*>(aB + swz(ln, s * 32))      = avS[set][0];
            *reinterpret_cast<short8*>(aB + swz(ln, s * 32 + 16)) = avS[set][1];
        }
    };
    auto issueW = [&](int j) {
        const u16* src = Wt + (size_t)ln * 576 + j * 64 + s * 16;
        wv2[0] = *reinterpret_cast<const short8*>(src);
        wv2[1] = *reinterpret_cast<const short8*>(src + 8);
    };
    auto writeW = [&](int buf) {
        char* wB = (char*)wL[buf];
        *reinterpret_cast<short8*>(wB + swz(ln, s * 32))      = wv2[0];
        *reinterpret_cast<short8*>(wB + swz(ln, s * 32 + 16)) = wv2[1];
    };
    auto stageWv = [&]() {
        const u16* src = Wvt + (size_t)ln * 64 + s * 16;
        short8 a = *reinterpret_cast<const short8*>(src);
        short8 b = *reinterpret_cast<const short8*>(src + 8);
        char* wB = (char*)wL[1];
        *reinterpret_cast<short8*>(wB + swz(ln, s * 32))      = a;
        *reinterpret_cast<short8*>(wB + swz(ln, s * 32 + 16)) = b;
    };

    // ---- accumulators: bias broadcast ----
    f32x4 acc[4];
    #pragma unroll
    for (int cf = 0; cf < 4; ++cf) {
        float b = bvec[cf * 16 + cq];
        acc[cf] = f32x4{b, b, b, b};
    }

    auto computeChunk = [&](int buf, f32x4* ac) {
        const char* aB = (const char*)aL[buf];
        const char* wB = (const char*)wL[buf];
        #pragma unroll
        for (int ks = 0; ks < 2; ++ks) {
            short8 afrag = *reinterpret_cast<const short8*>(
                aB + swz(w * 16 + cq, ks * 64 + kh * 16));
            #pragma unroll
            for (int cf = 0; cf < 4; ++cf) {
                short8 bfrag = *reinterpret_cast<const short8*>(
                    wB + swz(cf * 16 + cq, ks * 64 + kh * 16));
                ac[cf] = __builtin_amdgcn_mfma_f32_16x16x32_bf16(afrag, bfrag, ac[cf], 0, 0, 0);
            }
        }
    };

    // ---- prologue: A(0)->set0, A(1)->set1 in flight; A(0),W(0) -> LDS ----
    issueA(0, 0); issueA(1, 1); issueW(0);
    writeA(0, 0); writeW(0);
    __syncthreads();

    // ---- conv loop: 2 barriers/chunk, A prefetched 2 ahead ----
    for (int j = 0; j < 9; ++j) {
        if (j <= 6) issueA(j + 2, j & 1);
        if (j < 8) issueW(j + 1);
        computeChunk(j & 1, acc);
        __syncthreads();
        if (j < 8) {
            writeA((j + 1) & 1, (j + 1) & 1);
            writeW((j + 1) & 1);
        } else {
            // final chunk: stage head weights + relu'd hT into free buffers
            stageWv();
            char* hB = (char*)aL[1];
            #pragma unroll
            for (int cf = 0; cf < 4; ++cf)
                #pragma unroll
                for (int r = 0; r < 4; ++r) {
                    float hval = fmaxf(acc[cf][r], 0.f);
                    int row = w * 16 + kh * 4 + r;       // C/D: row=(l>>4)*4+r
                    int col = cf * 16 + cq;              //      col=l&15 (+16*cf)
                    *reinterpret_cast<u16*>(hB + swz(row, col * 2)) = f2bf(hval);
                }
        }
        __syncthreads();
    }

    // ---- value head: value = relu(h) @ Wv  (aL[1]=hT, wL[1]=Wv) ----
    f32x4 vacc[4];
    #pragma unroll
    for (int cf = 0; cf < 4; ++cf) vacc[cf] = f32x4{0.f, 0.f, 0.f, 0.f};
    computeChunk(1, vacc);

    #pragma unroll
    for (int cf = 0; cf < 4; ++cf)
        #pragma unroll
        for (int r = 0; r < 4; ++r) {
            int node = base + w * 16 + kh * 4 + r;
            if (node < N)   // NT store: pure streaming output, keep out of L3
                __builtin_nontemporal_store(
                    vacc[cf][r], value_out + (size_t)node * 64 + cf * 16 + cq);
        }

    // ---- parent: write bf16 h (ungated) to workspace, coalesced, CACHED ----
    if (MODE == 0 || MODE == 1) {
        int node = base + ln;
        if (node < N) {
            const char* hB = (const char*)aL[1];
            short8 x0 = *reinterpret_cast<const short8*>(hB + swz(ln, s * 32));
            short8 x1 = *reinterpret_cast<const short8*>(hB + swz(ln, s * 32 + 16));
            u16* dst = h_out + (size_t)node * 64 + s * 16;
            *reinterpret_cast<short8*>(dst)     = x0;
            *reinterpret_cast<short8*>(dst + 8) = x1;
        }
    }

    // ---- split head: split[n] = dot(h[n], Ws) ----
    {
        const char* hB = (const char*)aL[1];
        float sp = 0.f;
        #pragma unroll
        for (int u2 = 0; u2 < 2; ++u2) {
            short8 hv = *reinterpret_cast<const short8*>(hB + swz(ln, s * 32 + u2 * 16));
            #pragma unroll
            for (int e = 0; e < 8; ++e)
                sp += bf2f((u16)hv[e]) * Ws[s * 16 + u2 * 8 + e];
        }
        sp += __shfl_xor(sp, 1);
        sp += __shfl_xor(sp, 2);
        if (s == 0) {
            int node = base + ln;
            if (node < N)
                __builtin_nontemporal_store(sp, split_out + node);
        }
    }
}

extern "C" void kernel_launch(void* const* d_in, const int* in_sizes, int n_in,
                              void* d_out, int out_size, void* d_ws, size_t ws_size,
                              hipStream_t stream) {
    const float* feat       = (const float*)d_in[0];
    const int*   neigh_d    = (const int*)d_in[1];
    const int*   neigh_d1   = (const int*)d_in[2];
    const int*   parent_idx = (const int*)d_in[3];
    const float* split_gt   = (const float*)d_in[4];
    const float* W1  = (const float*)d_in[5];
    const float* b1  = (const float*)d_in[6];
    const float* W2  = (const float*)d_in[7];
    const float* b2  = (const float*)d_in[8];
    const float* Ws1 = (const float*)d_in[9];
    const float* Wv1 = (const float*)d_in[10];
    const float* Ws2 = (const float*)d_in[11];
    const float* Wv2 = (const float*)d_in[12];

    float* out    = (float*)d_out;
    float* split1 = out;
    float* value1 = out + NPARENT;
    float* split2 = out + NPARENT + (size_t)NPARENT * 64;
    float* value2 = split2 + NCHILD;

    // ---- workspace layout ----
    u16* h_ws = (u16*)d_ws;                          // [200000][64] bf16, ungated
    u16* Wt1  = h_ws + (size_t)NPARENT * 64;
    u16* Wt2  = Wt1 + 576 * 64;
    u16* Wv1t = Wt2 + 576 * 64;
    u16* Wv2t = Wv1t + 64 * 64;
    u16* endW = Wv2t + 64 * 64;
    size_t offW_bytes = (size_t)(endW - (u16*)d_ws) * 2;

    int*  fused = (int*)((char*)d_ws + offW_bytes);  // [300000][9] int32
    size_t offF_bytes = offW_bytes + (size_t)NCHILD * 9 * 4;
    u16*  featb = (u16*)((char*)d_ws + offF_bytes);  // [200000][64] bf16
    size_t offB_bytes = offF_bytes + (size_t)NPARENT * 64 * 2;

    const bool useFused = ws_size >= offF_bytes;
    const bool useFeatb = ws_size >= offB_bytes;

    const int bW = 145;                              // 145*256 >= 576*64
    const int bF = (NPARENT * 64 / 8 + 255) / 256;   // feat bf16 conversion
    const int bI = (NCHILD * 9 + 255) / 256;         // idx fusion
    prep_all<<<bW + bF + bI, 256, 0, stream>>>(
        W1, W2, Wv1, Wv2, feat, neigh_d1, parent_idx, split_gt,
        Wt1, Wt2, Wv1t, Wv2t, featb, fused,
        bW, bF, useFeatb ? 1 : 0, useFused ? 1 : 0);

    if (useFeatb)
        quad_mfma<1><<<NPARENT / 64, 256, 0, stream>>>(
            nullptr, featb, neigh_d, nullptr, nullptr,
            Wt1, b1, Ws1, Wv1t, split1, value1, h_ws, NPARENT);
    else
        quad_mfma<0><<<NPARENT / 64, 256, 0, stream>>>(
            feat, nullptr, neigh_d, nullptr, nullptr,
            Wt1, b1, Ws1, Wv1t, split1, value1, h_ws, NPARENT);

    if (useFused)
        quad_mfma<2><<<(NCHILD + 63) / 64, 256, 0, stream>>>(
            nullptr, h_ws, fused, nullptr, nullptr,
            Wt2, b2, Ws2, Wv2t, split2, value2, nullptr, NCHILD);
    else
        quad_mfma<3><<<(NCHILD + 63) / 64, 256, 0, stream>>>(
            nullptr, h_ws, neigh_d1, parent_idx, split_gt,
            Wt2, b2, Ws2, Wv2t, split2, value2, nullptr, NCHILD);
}